// Round 11
// baseline (915.414 us; speedup 1.0000x reference)
//
#include <hip/hip_runtime.h>
#include <math.h>

#define BB 4
#define CC 64
#define NN 8192
#define OO 128
#define KK 20
#define DD 128            // 2*CC
#define NCH 4             // candidate chunks per query
#define CH (NN / NCH)     // 2048 candidates per chunk
#define TC 32             // candidates per tile
#define NT (CH / TC)      // 64 tiles per sweep
#define BUFSZ 8           // per-lane append slots; checked per subtile (cnt<=4 -> +4 -> <=8)

typedef short bf16x8 __attribute__((ext_vector_type(8)));   // 8 bf16 (4 VGPR)
typedef float f32x4 __attribute__((ext_vector_type(4)));
typedef unsigned short u16x8 __attribute__((ext_vector_type(8)));
typedef unsigned long long u64;

typedef __attribute__((address_space(1))) const void gvoid;
typedef __attribute__((address_space(3))) void lvoid;

// orderable-key packing: (float value, candidate idx) -> u64, so that
// u64-descending == (value desc, idx asc). Matches jax.lax.top_k tie-breaking.
__device__ __forceinline__ u64 packkey(float v, int idx) {
  unsigned u = __float_as_uint(v);
  unsigned o = ((int)u < 0) ? ~u : (u | 0x80000000u);
  return (((u64)o) << 32) | (unsigned)(~idx);
}
__device__ __forceinline__ float keyval(u64 k) {
  unsigned o = (unsigned)(k >> 32);
  unsigned u = (o & 0x80000000u) ? (o ^ 0x80000000u) : ~o;
  return __uint_as_float(u);
}
#define INITKEY (((u64)0x007FFFFFu) << 32)   // packkey(-inf, 0xFFFFFFFF)

__device__ __forceinline__ unsigned short bf_rne(float f) {
  unsigned u = __float_as_uint(f);
  u += 0x7FFFu + ((u >> 16) & 1u);
  return (unsigned short)(u >> 16);
}
__device__ __forceinline__ float bf_f(unsigned short h) {
  return __uint_as_float(((unsigned)h) << 16);
}

// ---------------------------------------------------------------------------
// prep: xx[b][n] and xs[b][n][192] = 3-way bf16 split [h(64)|m(64)|l(64)],
// PRE-SWIZZLED: 16B-group at logical byte o lands at o ^ ((n&7)<<4).
// (unchanged)
// ---------------------------------------------------------------------------
__global__ __launch_bounds__(128) void prep_kernel(const float* __restrict__ x,
                                                   float* __restrict__ xx,
                                                   unsigned short* __restrict__ xs) {
  const int tid = threadIdx.x;
  const int b = blockIdx.y;
  const int n0 = blockIdx.x * 128;
  const float* xb = x + (size_t)b * CC * NN;
  float xv[CC];
  float acc = 0.0f;
  #pragma unroll
  for (int c = 0; c < CC; ++c) {
    float v = xb[(size_t)c * NN + n0 + tid];   // coalesced over tid
    acc += v * v;
    xv[c] = v;
  }
  xx[b * NN + n0 + tid] = acc;

  const int n = n0 + tid;
  char* xsrow = ((char*)xs) + ((size_t)b * NN + n) * 384;
  const int swn = (n & 7) << 4;
  #pragma unroll
  for (int gr = 0; gr < 8; ++gr) {
    u16x8 h8, m8, l8;
    #pragma unroll
    for (int e = 0; e < 8; ++e) {
      float v = xv[gr * 8 + e];
      unsigned short h = bf_rne(v);
      float r = v - bf_f(h);
      unsigned short m = bf_rne(r);
      r -= bf_f(m);
      unsigned short l = bf_rne(r);
      h8[e] = (unsigned short)h; m8[e] = m; l8[e] = l;
    }
    *(u16x8*)(xsrow + (((gr * 16) + 0) ^ swn)) = h8;
    *(u16x8*)(xsrow + (((gr * 16) + 128) ^ swn)) = m8;
    *(u16x8*)(xsrow + (((gr * 16) + 256) ^ swn)) = l8;
  }
}

// ---------------------------------------------------------------------------
// knn: MFMA distance matrix + per-lane buffered top-20.
// ROUND-11 (post-mortem r10: occupancy stuck at 37% because the GRID (1024
// blocks x 4 waves = 4096 waves) caps nominal occupancy at 50% -- the LDS
// diet was never the binding constraint. Also split pd/idx buffers had
// lane-stride 32B -> 8-way bank conflict on appends, 16.4M conflict cycles):
//  (1) NCH=4 -> grid 2048 x 4 waves = 8192 waves (100% nominal); LDS
//      24,704 B caps at 6 blocks/CU = 24 waves/CU. launch_bounds(256,4)
//      unchanged (spill-proven-safe; r8/r9's regressions were 2nd-arg
//      register starvation).
//  (2) TRANSPOSED append buffers [slot][lane]: append/rebuild = lane-stride-1
//      -> bank = lane%32, 2-way (free). Kills the 16.4M conflicts.
//  (3) tile-invariant LDS read offsets hoisted out of the tile loop.
// Selection math bit-identical to the r3-r7-r10 line. Epilogue + 4-way merge
// kernel = r8's correctness-proven pval/pidx form. XCD map: each XCD serves
// one (batch, chunk-pair) = 1.57MB, L2-resident.
// ---------------------------------------------------------------------------
__global__ __launch_bounds__(256, 4) void knn_kernel(
    const unsigned short* __restrict__ xs, const float* __restrict__ xx,
    float* __restrict__ pval, unsigned short* __restrict__ pidx) {
  __shared__ __attribute__((aligned(16))) unsigned short atile[TC * 192];  // 12288 B
  __shared__ __attribute__((aligned(16))) char bufmem[12288];              // 12288 B
  __shared__ float cxx[TC];                                                //   128 B
  float* pdb = (float*)bufmem;                        // [4*BUFSZ][64] f32 (8192 B)
  unsigned short* idb = (unsigned short*)(bufmem + 8192);  // [4*BUFSZ][64] u16 (4096 B)

  const int tid = threadIdx.x;
  const int w = tid >> 6;
  const int lane = tid & 63;
  const int r = lane & 15;    // query col (B) / cand row (A) within subtile
  const int g = lane >> 4;    // k-group
  // XCD-aware map: lin = qg*16 + chlo*8 + xcd (bijective over 2048)
  const int lin = blockIdx.x;
  const int xcd = lin & 7;
  const int b = xcd >> 1;
  const int ch = ((xcd & 1) << 1) | ((lin >> 3) & 1);
  const int qg = lin >> 4;           // [0,128)
  const int qbase = qg * 64 + w * 16;
  const int q = qbase + r;
  const int cbase = ch * CH;
  const char* xsb = ((const char*)xs) + (size_t)b * NN * 384;

  // query B-frags: bq[split][k-chunk]; lane holds k = (lane>>4)*8+[0..8) of 32
  bf16x8 bq[3][2];
  {
    const char* qrow = xsb + (size_t)q * 384;
    const int sw = (q & 7) << 4;
    #pragma unroll
    for (int s = 0; s < 3; ++s)
      #pragma unroll
      for (int c = 0; c < 2; ++c)
        bq[s][c] = *(const bf16x8*)(qrow + ((s * 128 + c * 64 + g * 16) ^ sw));
  }
  const float xxq = xx[b * NN + q];

  // tile-invariant LDS read offsets (12 ints)
  int aoff[2][6];
  {
    const int sw = (r & 7) << 4;
    #pragma unroll
    for (int ct = 0; ct < 2; ++ct)
      #pragma unroll
      for (int c6 = 0; c6 < 6; ++c6)
        aoff[ct][c6] = (ct * 16 + r) * 384 + ((c6 * 64 + g * 16) ^ sw);
  }

  u64 tk[KK];
  #pragma unroll
  for (int j = 0; j < KK; ++j) tk[j] = INITKEY;
  float minv = -INFINITY;
  int cnt = 0;
  float* pdl = pdb + w * (BUFSZ * 64) + lane;          // slot stride 64 (lane-major)
  unsigned short* idl = idb + w * (BUFSZ * 64) + lane;

  // stage tile t (12288 B: three 256-thread x 16B rounds)
  auto stage = [&](int t) {
    const char* src = xsb + (size_t)(cbase + t * TC) * 384;
    char* dst = (char*)atile;
    #pragma unroll
    for (int it = 0; it < 3; ++it) {
      __builtin_amdgcn_global_load_lds(
          (gvoid*)(src + it * 4096 + tid * 16),
          (lvoid*)(dst + it * 4096 + tid * 16), 16, 0, 0);
    }
    if (tid < 8)
      __builtin_amdgcn_global_load_lds(
          (gvoid*)(xx + b * NN + cbase + t * TC + tid * 4),
          (lvoid*)(cxx + tid * 4), 16, 0, 0);
  };

  // fold buffered candidates into the register-sorted top-20, tighten minv
  auto rebuild = [&]() {
    int mxc = cnt;
    #pragma unroll
    for (int o = 32; o > 0; o >>= 1) {
      int v = __shfl_xor(mxc, o);
      mxc = mxc > v ? mxc : v;
    }
    for (int i = 0; i < mxc; ++i) {
      u64 k = (i < cnt) ? packkey(pdl[i * 64], (int)idl[i * 64]) : 0ULL;
      if (k > tk[KK - 1]) {
        #pragma unroll
        for (int jj = KK - 1; jj >= 1; --jj)
          tk[jj] = (k > tk[jj - 1]) ? tk[jj - 1] : ((k > tk[jj]) ? k : tk[jj]);
        tk[0] = (k > tk[0]) ? k : tk[0];
      }
    }
    cnt = 0;
    minv = keyval(tk[KK - 1]);
  };

  for (int t = 0; t < NT; ++t) {
    stage(t);
    __syncthreads();   // vmcnt drained by compiler before barrier

    #pragma unroll
    for (int ct = 0; ct < 2; ++ct) {
      bf16x8 a6[6];
      #pragma unroll
      for (int c6 = 0; c6 < 6; ++c6)
        a6[c6] = *(const bf16x8*)(((const char*)atile) + aoff[ct][c6]);
      f32x4 acc = {0.f, 0.f, 0.f, 0.f};
      __builtin_amdgcn_s_setprio(1);
      #pragma unroll
      for (int s = 2; s >= 0; --s)   // b-split l,m first: small terms first
        #pragma unroll
        for (int c6 = 0; c6 < 6; ++c6)
          acc = __builtin_amdgcn_mfma_f32_16x16x32_bf16(a6[c6], bq[s][c6 & 1],
                                                        acc, 0, 0, 0);
      __builtin_amdgcn_s_setprio(0);

      // branchless pds + append gate (skips whole block once minv is tight)
      float pd0 = (-xxq - (-2.0f * acc[0])) - cxx[ct * 16 + g * 4 + 0];
      float pd1 = (-xxq - (-2.0f * acc[1])) - cxx[ct * 16 + g * 4 + 1];
      float pd2 = (-xxq - (-2.0f * acc[2])) - cxx[ct * 16 + g * 4 + 2];
      float pd3 = (-xxq - (-2.0f * acc[3])) - cxx[ct * 16 + g * 4 + 3];
      const float maxpd = fmaxf(fmaxf(pd0, pd1), fmaxf(pd2, pd3));
      if (__any(maxpd > minv)) {
        const int i0 = cbase + t * TC + ct * 16 + g * 4;
        if (pd0 > minv) { pdl[cnt * 64] = pd0; idl[cnt * 64] = (unsigned short)(i0 + 0); ++cnt; }
        if (pd1 > minv) { pdl[cnt * 64] = pd1; idl[cnt * 64] = (unsigned short)(i0 + 1); ++cnt; }
        if (pd2 > minv) { pdl[cnt * 64] = pd2; idl[cnt * 64] = (unsigned short)(i0 + 2); ++cnt; }
        if (pd3 > minv) { pdl[cnt * 64] = pd3; idl[cnt * 64] = (unsigned short)(i0 + 3); ++cnt; }
        // invariant: cnt<=4 entering a subtile; +4 appends -> <=8 = BUFSZ
        if (__any(cnt > BUFSZ - 4)) rebuild();
      }
    }
    __syncthreads();   // atile consumed; next stage may overwrite
  }

  rebuild();   // flush remaining buffered candidates

  // --- epilogue: 4-class in-block merge -> pval/pidx[q][ch][20] ---
  // atile (12,288 B) is dead; one wave at a time uses it (64x20 u64 = 10,240 B).
  for (int pass = 0; pass < 4; ++pass) {
    __syncthreads();
    if (w == pass) {
      u64* ml = (u64*)atile;
      #pragma unroll
      for (int j = 0; j < KK; ++j) ml[lane * KK + j] = tk[j];
      // same-wave LDS write->read: in-order, compiler inserts lgkmcnt
      if (lane < 16) {
        const size_t qn = (size_t)b * NN + qbase + lane;
        float* po = pval + (qn * NCH + ch) * KK;
        unsigned short* io = pidx + (qn * NCH + ch) * KK;
        const u64* L0 = ml + (lane + 0) * KK;
        const u64* L1 = ml + (lane + 16) * KK;
        const u64* L2 = ml + (lane + 32) * KK;
        const u64* L3 = ml + (lane + 48) * KK;
        int p0 = 0, p1 = 0, p2 = 0, p3 = 0;
        u64 h0 = L0[0], h1 = L1[0], h2 = L2[0], h3 = L3[0];
        #pragma unroll
        for (int k = 0; k < KK; ++k) {
          u64 bv = h0; int bc = 0;
          if (h1 > bv) { bv = h1; bc = 1; }
          if (h2 > bv) { bv = h2; bc = 2; }
          if (h3 > bv) { bv = h3; bc = 3; }
          po[k] = keyval(bv);
          io[k] = (unsigned short)(~(unsigned)bv);
          if (bc == 0)      { ++p0; h0 = (p0 < KK) ? L0[p0] : 0ULL; }
          else if (bc == 1) { ++p1; h1 = (p1 < KK) ? L1[p1] : 0ULL; }
          else if (bc == 2) { ++p2; h2 = (p2 < KK) ? L2[p2] : 0ULL; }
          else              { ++p3; h3 = (p3 < KK) ? L3[p3] : 0ULL; }
        }
      }
    }
  }
}

// ---------------------------------------------------------------------------
// merge: per query, 4-way merge of sorted chunk lists (value desc, idx asc).
// Chunks partition index ranges; explicit tie-break matches jax.lax.top_k.
// (r8's correctness-proven version)
// ---------------------------------------------------------------------------
__global__ __launch_bounds__(256) void merge_kernel(const float* __restrict__ pval,
                                                    const unsigned short* __restrict__ pidx,
                                                    int* __restrict__ fidx) {
  const int qn = blockIdx.x * 256 + threadIdx.x;   // qn = b*NN + n
  const float* pv = pval + (size_t)qn * NCH * KK;
  const unsigned short* pi = pidx + (size_t)qn * NCH * KK;
  int* fo = fidx + (size_t)qn * KK;
  int p0 = 0, p1 = 0, p2 = 0, p3 = 0;
  float v0 = pv[0], v1 = pv[KK], v2 = pv[2 * KK], v3 = pv[3 * KK];
  int i0 = pi[0], i1 = pi[KK], i2 = pi[2 * KK], i3 = pi[3 * KK];
  #pragma unroll
  for (int k = 0; k < KK; ++k) {
    float bv = v0; int bi = i0; int bc = 0;
    if (v1 > bv || (v1 == bv && i1 < bi)) { bv = v1; bi = i1; bc = 1; }
    if (v2 > bv || (v2 == bv && i2 < bi)) { bv = v2; bi = i2; bc = 2; }
    if (v3 > bv || (v3 == bv && i3 < bi)) { bv = v3; bi = i3; bc = 3; }
    fo[k] = bi;
    if (bc == 0)      { ++p0; v0 = (p0 < KK) ? pv[p0] : -INFINITY;          i0 = (p0 < KK) ? pi[p0] : 0x7fffffff; }
    else if (bc == 1) { ++p1; v1 = (p1 < KK) ? pv[KK + p1] : -INFINITY;     i1 = (p1 < KK) ? pi[KK + p1] : 0x7fffffff; }
    else if (bc == 2) { ++p2; v2 = (p2 < KK) ? pv[2 * KK + p2] : -INFINITY; i2 = (p2 < KK) ? pi[2 * KK + p2] : 0x7fffffff; }
    else              { ++p3; v3 = (p3 < KK) ? pv[3 * KK + p3] : -INFINITY; i3 = (p3 < KK) ? pi[3 * KK + p3] : 0x7fffffff; }
  }
}

// ---------------------------------------------------------------------------
// w1prep: pre-pack W1a^T as 3-way bf16-split MFMA B-frags. (unchanged)
// ---------------------------------------------------------------------------
__global__ __launch_bounds__(256) void w1prep_kernel(const float* __restrict__ W1,
                                                     unsigned short* __restrict__ w1p) {
  for (int e = threadIdx.x; e < 12288; e += 256) {
    const int f = e >> 9;
    const int rr = e & 511;
    const int l = rr >> 3;
    const int j = rr & 7;
    const int pair = f / 3, s = f % 3;
    const int dt = pair >> 1, kc = pair & 1;
    const int d = dt * 16 + (l & 15);
    const int c = kc * 32 + (l >> 4) * 8 + j;
    const float v = W1[d * DD + c];
    const unsigned short h = bf_rne(v);
    float r = v - bf_f(h);
    const unsigned short m = bf_rne(r);
    r -= bf_f(m);
    const unsigned short lo = bf_rne(r);
    w1p[(size_t)f * 512 + l * 8 + j] = (s == 0) ? h : ((s == 1) ? m : lo);
  }
}

#define MFMA16(A, B, C) __builtin_amdgcn_mfma_f32_16x16x32_bf16((A), (B), (C), 0, 0, 0)

// one h-GEMM cross term (SA = A split, SB = B split), indices compile-time
template <int SA, int SB>
__device__ __forceinline__ void h_term(const bf16x8 (&a)[3][2][2],
                                       const bf16x8 (&w1f)[24],
                                       f32x4 (&acc)[4][2]) {
  #pragma unroll
  for (int dt = 0; dt < 4; ++dt)
    #pragma unroll
    for (int kc = 0; kc < 2; ++kc) {
      const bf16x8 bf = w1f[(dt * 2 + kc) * 3 + SB];
      acc[dt][0] = MFMA16(a[SA][kc][0], bf, acc[dt][0]);
      acc[dt][1] = MFMA16(a[SA][kc][1], bf, acc[dt][1]);
    }
}

// epilogue for d-tile DT: Y re-layout via identity-B MFMA, masked softmax
// over k (shfl_xor across the 4 lane-groups), returns T[d] = sum_k y_k[d]*gate
template <int DT>
__device__ __forceinline__ float d1_epi(const bf16x8 (&a)[3][2][2],
                                        bf16x8 id0, bf16x8 id1,
                                        const f32x4 (&acc)[4][2], int g) {
  constexpr int KC = DT >> 1;
  const bf16x8 idp = (DT & 1) ? id1 : id0;
  f32x4 yf0 = {0.f, 0.f, 0.f, 0.f}, yf1 = {0.f, 0.f, 0.f, 0.f};
  yf0 = MFMA16(a[1][KC][0], idp, yf0);   // m split first (smaller)
  yf0 = MFMA16(a[0][KC][0], idp, yf0);
  yf1 = MFMA16(a[1][KC][1], idp, yf1);
  yf1 = MFMA16(a[0][KC][1], idp, yf1);
  const f32x4 h0 = acc[DT][0], h1 = acc[DT][1];
  float mx = fmaxf(fmaxf(h0[0], h0[1]), fmaxf(h0[2], h0[3]));
  mx = fmaxf(mx, fmaxf(fmaxf(h1[0], h1[1]), fmaxf(h1[2], h1[3])));  // dups harmless
  mx = fmaxf(mx, __shfl_xor(mx, 16));
  mx = fmaxf(mx, __shfl_xor(mx, 32));
  float sl = 0.f, tl = 0.f;
  #pragma unroll
  for (int j = 0; j < 4; ++j) {
    const float e = __expf(h0[j] - mx);
    sl += e; tl += yf0[j] * e;
  }
  if (g == 0) {   // tile1 rows k=16..19 counted exactly once (dup groups masked)
    #pragma unroll
    for (int j = 0; j < 4; ++j) {
      const float e = __expf(h1[j] - mx);
      sl += e; tl += yf1[j] * e;
    }
  }
  sl += __shfl_xor(sl, 16); sl += __shfl_xor(sl, 32);
  tl += __shfl_xor(tl, 16); tl += __shfl_xor(tl, 32);
  return tl / sl;
}

// ---------------------------------------------------------------------------
// d1 (MFMA rewrite; unchanged from round-3 pass).
// ---------------------------------------------------------------------------
__global__ __launch_bounds__(256, 2) void d1_kernel(
    const unsigned short* __restrict__ xs, const int* __restrict__ fidx,
    const unsigned short* __restrict__ w1p, float* __restrict__ gbuf) {
  const int tid = threadIdx.x;
  const int w = tid >> 6;
  const int lane = tid & 63;
  const int r = lane & 15;
  const int g = lane >> 4;
  const int b = blockIdx.y;
  const char* xsb = ((const char*)xs) + (size_t)b * NN * 384;

  // hoisted n-invariant B-frags (96 VGPR)
  bf16x8 w1f[24];
  #pragma unroll
  for (int f = 0; f < 24; ++f)
    w1f[f] = *(const bf16x8*)(((const char*)w1p) + f * 1024 + lane * 16);

  // identity B-frags: select cols [p*16, p*16+16) of the K=32 chunk
  bf16x8 id0, id1;
  #pragma unroll
  for (int j = 0; j < 8; ++j) {
    id0[j] = (g == (r >> 3) && j == (r & 7)) ? (short)0x3F80 : (short)0;
    id1[j] = (g == 2 + (r >> 3) && j == (r & 7)) ? (short)0x3F80 : (short)0;
  }

  for (int i = 0; i < 4; ++i) {
    const int n = blockIdx.x * 16 + w * 4 + i;
    const size_t ng = (size_t)b * NN + n;
    const int* kp = fidx + ng * KK;
    const int row0 = kp[r];                 // tile0 row r -> neighbor r
    const int row1 = kp[16 + (r & 3)];      // tile1 row r -> neighbor 16+(r&3)
    const char* rp0 = xsb + (size_t)row0 * 384;
    const char* rp1 = xsb + (size_t)row1 * 384;
    const int sw0 = (row0 & 7) << 4, sw1 = (row1 & 7) << 4;

    bf16x8 a[3][2][2];
    #pragma unroll
    for (int s = 0; s < 3; ++s)
      #pragma unroll
      for (int kc = 0; kc < 2; ++kc) {
        const int off = s * 128 + kc * 64 + g * 16;
        a[s][kc][0] = *(const bf16x8*)(rp0 + (off ^ sw0));
        a[s][kc][1] = *(const bf16x8*)(rp1 + (off ^ sw1));
      }

    // z[c=lane] reconstructed to ~2^-27
    const char* zrow = xsb + (size_t)n * 384;
    const int swn = (n & 7) << 4;
    float zl;
    {
      const unsigned short zh = *(const unsigned short*)(zrow + ((2 * lane) ^ swn));
      const unsigned short zm = *(const unsigned short*)(zrow + ((128 + 2 * lane) ^ swn));
      const unsigned short zo = *(const unsigned short*)(zrow + ((256 + 2 * lane) ^ swn));
      zl = bf_f(zh) + bf_f(zm) + bf_f(zo);
    }

    f32x4 acc[4][2];
    #pragma unroll
    for (int dt = 0; dt < 4; ++dt) {
      acc[dt][0] = (f32x4){0.f, 0.f, 0.f, 0.f};
      acc[dt][1] = (f32x4){0.f, 0.f, 0.f, 0.f};
    }
    // smallest cross terms first
    h_term<2, 0>(a, w1f, acc);
    h_term<0, 2>(a, w1f, acc);
    h_term<1, 1>(a, w1f, acc);
    h_term<1, 0>(a, w1f, acc);
    h_term<0, 1>(a, w1f, acc);
    h_term<0, 0>(a, w1f, acc);

    const float t0 = d1_epi<0>(a, id0, id1, acc, g);
    const float t1 = d1_epi<1>(a, id0, id1, acc, g);
    const float t2 = d1_epi<2>(a, id0, id1, acc, g);
    const float t3 = d1_epi<3>(a, id0, id1, acc, g);

    float* go = gbuf + ng * DD;
    go[64 + lane] = zl;                     // g[d>=64] = z  (sum gate == 1)
    const float z0 = __shfl(zl, r);
    const float z1 = __shfl(zl, 16 + r);
    const float z2 = __shfl(zl, 32 + r);
    const float z3 = __shfl(zl, 48 + r);
    if (lane < 16) {
      go[r]      = t0 - z0;
      go[16 + r] = t1 - z1;
      go[32 + r] = t2 - z2;
      go[48 + r] = t3 - z3;
    }
  }
}

// ---------------------------------------------------------------------------
// d2: out[b][o][n] = sum_c g[b][n][c] * W2[o][c]. (unchanged)
// ---------------------------------------------------------------------------
__global__ __launch_bounds__(256) void d2_kernel(const float* __restrict__ gbuf,
                                                 const float* __restrict__ W2,
                                                 float* __restrict__ out) {
  __shared__ float4 w2s[OO * 32];  // addr4 = o*32 + (c4 ^ (o&7))
  const int tid = threadIdx.x;
  const int b = blockIdx.y;
  const int n0 = blockIdx.x * 32;
  const float4* w2v = (const float4*)W2;
  for (int t = tid; t < OO * 32; t += 256) {
    int o = t >> 5, c4 = t & 31;
    w2s[o * 32 + (c4 ^ (o & 7))] = w2v[t];
  }
  __syncthreads();
  const int og = tid & 7;
  const int ni = tid >> 3;
  const int n = n0 + ni;
  const float4* gp = (const float4*)(gbuf + ((size_t)b * NN + n) * DD);
  float acc[16];
  #pragma unroll
  for (int j = 0; j < 16; ++j) acc[j] = 0.0f;
  for (int c4 = 0; c4 < 32; ++c4) {
    float4 g4 = gp[c4];
    #pragma unroll
    for (int j = 0; j < 16; ++j) {
      const int o = j * 8 + og;
      float4 w4 = w2s[o * 32 + (c4 ^ og)];
      acc[j] += g4.x * w4.x + g4.y * w4.y + g4.z * w4.z + g4.w * w4.w;
    }
  }
  float* outb = out + (size_t)b * OO * NN;
  #pragma unroll
  for (int j = 0; j < 16; ++j) {
    outb[(size_t)(j * 8 + og) * NN + n] = acc[j];
  }
}

// ---------------------------------------------------------------------------
// ws layout (bytes):
//   xs    @ 0          : 6,291,456 u16 = 12,582,912 B  (live: prep->knn,d1)
//   xx    @ 12,582,912 :    32,768 f32 =    131,072 B  (live: prep->knn)
//   w1p   @ 12,582,912 :    12,288 u16 =     24,576 B  (aliases dead xx; w1prep->d1)
//   fidx  @ 12,713,984 :   655,360 i32 =  2,621,440 B  (live: merge->d1)
//   pval  @ 15,335,424 : 2,621,440 f32 = 10,485,760 B  (live: knn->merge)
//   pidx  @ 25,821,184 : 2,621,440 u16 =  5,242,880 B  (live: knn->merge)
//   gbuf  @ 15,335,424 : 4,194,304 f32 = 16,777,216 B  (live: d1->d2; reuses pval/pidx)
// total: 32,112,640 B
// ---------------------------------------------------------------------------
extern "C" void kernel_launch(void* const* d_in, const int* in_sizes, int n_in,
                              void* d_out, int out_size, void* d_ws, size_t ws_size,
                              hipStream_t stream) {
  const float* x  = (const float*)d_in[0];
  const float* W1 = (const float*)d_in[1];
  const float* W2 = (const float*)d_in[2];
  float* out = (float*)d_out;
  char* ws = (char*)d_ws;
  unsigned short* xs = (unsigned short*)(ws);
  float* xx = (float*)(ws + 12582912);
  unsigned short* w1p = (unsigned short*)(ws + 12582912);
  int* fidx = (int*)(ws + 12713984);
  float* pval = (float*)(ws + 15335424);
  unsigned short* pidx = (unsigned short*)(ws + 25821184);
  float* gbuf = (float*)(ws + 15335424);

  prep_kernel<<<dim3(NN / 128, BB), 128, 0, stream>>>(x, xx, xs);
  knn_kernel<<<dim3(2048), 256, 0, stream>>>(xs, xx, pval, pidx);  // 8192 waves
  merge_kernel<<<dim3(BB * NN / 256), 256, 0, stream>>>(pval, pidx, fidx);
  w1prep_kernel<<<dim3(1), 256, 0, stream>>>(W1, w1p);             // after knn: xx dead
  d1_kernel<<<dim3(NN / 16, BB), 256, 0, stream>>>(xs, fidx, w1p, gbuf);
  d2_kernel<<<dim3(NN / 32, BB), 256, 0, stream>>>(gbuf, W2, out);
}

// Round 13
// 707.139 us; speedup vs baseline: 1.2945x; 1.2945x over previous
//
#include <hip/hip_runtime.h>
#include <math.h>

#define BB 4
#define CC 64
#define NN 8192
#define OO 128
#define KK 20
#define DD 128            // 2*CC
#define NCH 2             // candidate chunks per query
#define CH (NN / NCH)     // 4096 candidates per chunk
#define TC 64             // candidates per tile (r7-proven)
#define NT (CH / TC)      // 64 tiles per sweep
#define BUFSZ 8           // per-lane append slots; checked per subtile (cnt<=4 -> +4 -> <=8)

typedef short bf16x8 __attribute__((ext_vector_type(8)));   // 8 bf16 (4 VGPR)
typedef float f32x4 __attribute__((ext_vector_type(4)));
typedef unsigned short u16x8 __attribute__((ext_vector_type(8)));
typedef unsigned long long u64;

typedef __attribute__((address_space(1))) const void gvoid;
typedef __attribute__((address_space(3))) void lvoid;

#define MFMA16(A, B, C) __builtin_amdgcn_mfma_f32_16x16x32_bf16((A), (B), (C), 0, 0, 0)

// orderable-key packing: (float value, candidate idx) -> u64, so that
// u64-descending == (value desc, idx asc). Matches jax.lax.top_k tie-breaking.
__device__ __forceinline__ u64 packkey(float v, int idx) {
  unsigned u = __float_as_uint(v);
  unsigned o = ((int)u < 0) ? ~u : (u | 0x80000000u);
  return (((u64)o) << 32) | (unsigned)(~idx);
}
__device__ __forceinline__ float keyval(u64 k) {
  unsigned o = (unsigned)(k >> 32);
  unsigned u = (o & 0x80000000u) ? (o ^ 0x80000000u) : ~o;
  return __uint_as_float(u);
}
#define INITKEY (((u64)0x007FFFFFu) << 32)   // packkey(-inf, 0xFFFFFFFF)

__device__ __forceinline__ unsigned short bf_rne(float f) {
  unsigned u = __float_as_uint(f);
  u += 0x7FFFu + ((u >> 16) & 1u);
  return (unsigned short)(u >> 16);
}
__device__ __forceinline__ float bf_f(unsigned short h) {
  return __uint_as_float(((unsigned)h) << 16);
}

// ---------------------------------------------------------------------------
// prep: xx[b][n] and xs[b][n][192] = 3-way bf16 split [h(64)|m(64)|l(64)],
// PRE-SWIZZLED: 16B-group at logical byte o lands at o ^ ((n&7)<<4).
// (unchanged)
// ---------------------------------------------------------------------------
__global__ __launch_bounds__(128) void prep_kernel(const float* __restrict__ x,
                                                   float* __restrict__ xx,
                                                   unsigned short* __restrict__ xs) {
  const int tid = threadIdx.x;
  const int b = blockIdx.y;
  const int n0 = blockIdx.x * 128;
  const float* xb = x + (size_t)b * CC * NN;
  float xv[CC];
  float acc = 0.0f;
  #pragma unroll
  for (int c = 0; c < CC; ++c) {
    float v = xb[(size_t)c * NN + n0 + tid];   // coalesced over tid
    acc += v * v;
    xv[c] = v;
  }
  xx[b * NN + n0 + tid] = acc;

  const int n = n0 + tid;
  char* xsrow = ((char*)xs) + ((size_t)b * NN + n) * 384;
  const int swn = (n & 7) << 4;
  #pragma unroll
  for (int gr = 0; gr < 8; ++gr) {
    u16x8 h8, m8, l8;
    #pragma unroll
    for (int e = 0; e < 8; ++e) {
      float v = xv[gr * 8 + e];
      unsigned short h = bf_rne(v);
      float r = v - bf_f(h);
      unsigned short m = bf_rne(r);
      r -= bf_f(m);
      unsigned short l = bf_rne(r);
      h8[e] = (unsigned short)h; m8[e] = m; l8[e] = l;
    }
    *(u16x8*)(xsrow + (((gr * 16) + 0) ^ swn)) = h8;
    *(u16x8*)(xsrow + (((gr * 16) + 128) ^ swn)) = m8;
    *(u16x8*)(xsrow + (((gr * 16) + 256) ^ swn)) = l8;
  }
}

// ---------------------------------------------------------------------------
// knn: MFMA distance matrix + per-lane buffered top-20.
// ROUND-13 (post-mortem r12: dropping the m*l/l*m/l*l cross terms (-33%
// MFMA) added ~5e-7 dot error and FLIPPED a rank-20 selection -> absmax
// 0.2168 FAIL. knn's dot must stay bit-identical to the 7x-passing 18-MFMA
// line -- selection is not error-tolerant the way d1's softmax is):
// r7 structure + EXACT r7 MFMA arithmetic (18 MFMAs, s=2..0 x c6=0..5
// order -> selection bit-identical to r3/r4/r5/r6/r7/r10/r11 passes), plus
// the two semantics-preserving micro-opts from r11/r12:
//  (1) transposed append buffers [slot][lane]: bank = lane%32 regardless of
//      divergent cnt -> 2-way (free, m136). r7 had 3.1M conflict cycles.
//  (2) tile-invariant LDS read offsets hoisted (+24 VGPR, << 128 cap).
// launch_bounds(256,4): the only spill-safe bound (r8 (512,8)->VGPR32 spill;
// r9 (256,6)->VGPR40 spill; (256,4) -> VGPR 60-64, no spill).
// LDS 37,120 B -> 4 blocks/CU = 16 waves/CU (r7's proven operating point).
// ---------------------------------------------------------------------------
__global__ __launch_bounds__(256, 4) void knn_kernel(
    const unsigned short* __restrict__ xs, const float* __restrict__ xx,
    u64* __restrict__ pkeys) {
  __shared__ __attribute__((aligned(16))) unsigned short atile[TC * 192];  // 24576 B
  __shared__ __attribute__((aligned(16))) char bufmem[12288];              // 12288 B
  __shared__ float cxx[TC];                                                //   256 B
  float* pdb = (float*)bufmem;                        // [4][BUFSZ][64] f32 (8192 B)
  unsigned short* idb = (unsigned short*)(bufmem + 8192);  // [4][BUFSZ][64] u16

  const int tid = threadIdx.x;
  const int w = tid >> 6;
  const int lane = tid & 63;
  const int r = lane & 15;    // query col (B) / cand row (A) within subtile
  const int g = lane >> 4;    // k-group
  // XCD-aware map (r7): lin = qg*8 + b*2 + ch; each XCD serves one
  // (batch, chunk): 1.57MB candidate rows, L2-resident.
  const int lin = blockIdx.x;
  const int xcd = lin & 7;
  const int b = xcd >> 1;
  const int ch = xcd & 1;
  const int qg = lin >> 3;           // [0,128)
  const int qbase = qg * 64 + w * 16;
  const int q = qbase + r;
  const int cbase = ch * CH;
  const char* xsb = ((const char*)xs) + (size_t)b * NN * 384;

  // query B-frags: bq[split][k-chunk]; lane holds k = (lane>>4)*8+[0..8) of 32
  bf16x8 bq[3][2];
  {
    const char* qrow = xsb + (size_t)q * 384;
    const int sw = (q & 7) << 4;
    #pragma unroll
    for (int s = 0; s < 3; ++s)
      #pragma unroll
      for (int c = 0; c < 2; ++c)
        bq[s][c] = *(const bf16x8*)(qrow + ((s * 128 + c * 64 + g * 16) ^ sw));
  }
  const float xxq = xx[b * NN + q];

  // tile-invariant LDS read offsets (24 ints)
  int aoff[4][6];
  {
    const int sw = (r & 7) << 4;
    #pragma unroll
    for (int ct = 0; ct < 4; ++ct)
      #pragma unroll
      for (int c6 = 0; c6 < 6; ++c6)
        aoff[ct][c6] = (ct * 16 + r) * 384 + ((c6 * 64 + g * 16) ^ sw);
  }

  u64 tk[KK];
  #pragma unroll
  for (int j = 0; j < KK; ++j) tk[j] = INITKEY;
  float minv = -INFINITY;
  int cnt = 0;
  float* pdl = pdb + w * (BUFSZ * 64) + lane;          // [slot][lane]: stride 64
  unsigned short* idl = idb + w * (BUFSZ * 64) + lane;

  // stage tile t (24576 B: six 256-thread x 16B rounds; r7 shape)
  auto stage = [&](int t) {
    const char* src = xsb + (size_t)(cbase + t * TC) * 384;
    char* dst = (char*)atile;
    #pragma unroll
    for (int it = 0; it < 6; ++it) {
      __builtin_amdgcn_global_load_lds(
          (gvoid*)(src + it * 4096 + tid * 16),
          (lvoid*)(dst + it * 4096 + tid * 16), 16, 0, 0);
    }
    if (tid < 16)
      __builtin_amdgcn_global_load_lds(
          (gvoid*)(xx + b * NN + cbase + t * TC + tid * 4),
          (lvoid*)(cxx + tid * 4), 16, 0, 0);
  };

  // fold buffered candidates into the register-sorted top-20, tighten minv
  auto rebuild = [&]() {
    int mxc = cnt;
    #pragma unroll
    for (int o = 32; o > 0; o >>= 1) {
      int v = __shfl_xor(mxc, o);
      mxc = mxc > v ? mxc : v;
    }
    for (int i = 0; i < mxc; ++i) {
      u64 k = (i < cnt) ? packkey(pdl[i * 64], (int)idl[i * 64]) : 0ULL;
      if (k > tk[KK - 1]) {
        #pragma unroll
        for (int jj = KK - 1; jj >= 1; --jj)
          tk[jj] = (k > tk[jj - 1]) ? tk[jj - 1] : ((k > tk[jj]) ? k : tk[jj]);
        tk[0] = (k > tk[0]) ? k : tk[0];
      }
    }
    cnt = 0;
    minv = keyval(tk[KK - 1]);
  };

  for (int t = 0; t < NT; ++t) {
    stage(t);
    __syncthreads();   // vmcnt drained by compiler before barrier

    #pragma unroll
    for (int ct = 0; ct < 4; ++ct) {
      bf16x8 a6[6];
      #pragma unroll
      for (int c6 = 0; c6 < 6; ++c6)
        a6[c6] = *(const bf16x8*)(((const char*)atile) + aoff[ct][c6]);
      f32x4 acc = {0.f, 0.f, 0.f, 0.f};
      __builtin_amdgcn_s_setprio(1);
      // FULL 9-term cross product, EXACT r7 order (s=2..0, c6=0..5):
      // selection bit-identical to every passing round.
      #pragma unroll
      for (int s = 2; s >= 0; --s)
        #pragma unroll
        for (int c6 = 0; c6 < 6; ++c6)
          acc = MFMA16(a6[c6], bq[s][c6 & 1], acc);
      __builtin_amdgcn_s_setprio(0);

      // branchless pds + append gate (skips whole block once minv is tight)
      float pd0 = (-xxq - (-2.0f * acc[0])) - cxx[ct * 16 + g * 4 + 0];
      float pd1 = (-xxq - (-2.0f * acc[1])) - cxx[ct * 16 + g * 4 + 1];
      float pd2 = (-xxq - (-2.0f * acc[2])) - cxx[ct * 16 + g * 4 + 2];
      float pd3 = (-xxq - (-2.0f * acc[3])) - cxx[ct * 16 + g * 4 + 3];
      const float maxpd = fmaxf(fmaxf(pd0, pd1), fmaxf(pd2, pd3));
      if (__any(maxpd > minv)) {
        const int i0 = cbase + t * TC + ct * 16 + g * 4;
        if (pd0 > minv) { pdl[cnt * 64] = pd0; idl[cnt * 64] = (unsigned short)(i0 + 0); ++cnt; }
        if (pd1 > minv) { pdl[cnt * 64] = pd1; idl[cnt * 64] = (unsigned short)(i0 + 1); ++cnt; }
        if (pd2 > minv) { pdl[cnt * 64] = pd2; idl[cnt * 64] = (unsigned short)(i0 + 2); ++cnt; }
        if (pd3 > minv) { pdl[cnt * 64] = pd3; idl[cnt * 64] = (unsigned short)(i0 + 3); ++cnt; }
        // invariant: cnt<=4 entering a subtile; +4 appends -> <=8 = BUFSZ
        if (__any(cnt > BUFSZ - 4)) rebuild();
      }
    }
    __syncthreads();   // atile consumed; next stage may overwrite
  }

  rebuild();   // flush remaining buffered candidates

  // --- epilogue: 4-class in-block merge -> pkeys[q][ch][20] (r9-proven) ---
  // atile (24,576 B) + bufmem (12,288 B) dead; 2 waves per pass, 10,240 B each.
  for (int pass = 0; pass < 2; ++pass) {
    __syncthreads();
    if ((w >> 1) == pass) {
      u64* ml = (w & 1) ? (u64*)bufmem : (u64*)atile;
      #pragma unroll
      for (int j = 0; j < KK; ++j) ml[lane * KK + j] = tk[j];
      // same-wave LDS write->read: in-order, compiler inserts lgkmcnt
      if (lane < 16) {
        u64* po = pkeys + (((size_t)b * NN + qbase + lane) * NCH + ch) * KK;
        const u64* L0 = ml + (lane + 0) * KK;
        const u64* L1 = ml + (lane + 16) * KK;
        const u64* L2 = ml + (lane + 32) * KK;
        const u64* L3 = ml + (lane + 48) * KK;
        int p0 = 0, p1 = 0, p2 = 0, p3 = 0;
        u64 h0 = L0[0], h1 = L1[0], h2 = L2[0], h3 = L3[0];
        #pragma unroll
        for (int k = 0; k < KK; ++k) {
          u64 bv = h0; int bc = 0;
          if (h1 > bv) { bv = h1; bc = 1; }
          if (h2 > bv) { bv = h2; bc = 2; }
          if (h3 > bv) { bv = h3; bc = 3; }
          po[k] = bv;
          if (bc == 0)      { ++p0; h0 = (p0 < KK) ? L0[p0] : 0ULL; }
          else if (bc == 1) { ++p1; h1 = (p1 < KK) ? L1[p1] : 0ULL; }
          else if (bc == 2) { ++p2; h2 = (p2 < KK) ? L2[p2] : 0ULL; }
          else              { ++p3; h3 = (p3 < KK) ? L3[p3] : 0ULL; }
        }
      }
    }
  }
}

// ---------------------------------------------------------------------------
// merge: per query, 2-way merge of the two chunk lists (sorted desc u64).
// Chunks partition index ranges; u64 compare embeds (value desc, idx asc).
// (r7/r9/r10-proven)
// ---------------------------------------------------------------------------
__global__ __launch_bounds__(256) void merge_kernel(const u64* __restrict__ pkeys,
                                                    int* __restrict__ fidx) {
  const int q = blockIdx.x * 256 + threadIdx.x;   // q = b*NN + n
  const u64* pk = pkeys + (size_t)q * NCH * KK;
  int* fo = fidx + (size_t)q * KK;
  int p0 = 0, p1 = 0;
  u64 h0 = pk[0], h1 = pk[KK];
  #pragma unroll
  for (int k = 0; k < KK; ++k) {
    const bool t1 = h1 > h0;
    const u64 bv = t1 ? h1 : h0;
    fo[k] = (int)(~(unsigned)bv);
    if (t1) { ++p1; h1 = (p1 < KK) ? pk[KK + p1] : 0ULL; }
    else    { ++p0; h0 = (p0 < KK) ? pk[p0] : 0ULL; }
  }
}

// ---------------------------------------------------------------------------
// w1prep: pre-pack W1a^T as 3-way bf16-split MFMA B-frags. (unchanged)
// ---------------------------------------------------------------------------
__global__ __launch_bounds__(256) void w1prep_kernel(const float* __restrict__ W1,
                                                     unsigned short* __restrict__ w1p) {
  for (int e = threadIdx.x; e < 12288; e += 256) {
    const int f = e >> 9;
    const int rr = e & 511;
    const int l = rr >> 3;
    const int j = rr & 7;
    const int pair = f / 3, s = f % 3;
    const int dt = pair >> 1, kc = pair & 1;
    const int d = dt * 16 + (l & 15);
    const int c = kc * 32 + (l >> 4) * 8 + j;
    const float v = W1[d * DD + c];
    const unsigned short h = bf_rne(v);
    float r = v - bf_f(h);
    const unsigned short m = bf_rne(r);
    r -= bf_f(m);
    const unsigned short lo = bf_rne(r);
    w1p[(size_t)f * 512 + l * 8 + j] = (s == 0) ? h : ((s == 1) ? m : lo);
  }
}

// one h-GEMM cross term (SA = A split, SB = B split), indices compile-time
template <int SA, int SB>
__device__ __forceinline__ void h_term(const bf16x8 (&a)[3][2][2],
                                       const bf16x8 (&w1f)[24],
                                       f32x4 (&acc)[4][2]) {
  #pragma unroll
  for (int dt = 0; dt < 4; ++dt)
    #pragma unroll
    for (int kc = 0; kc < 2; ++kc) {
      const bf16x8 bf = w1f[(dt * 2 + kc) * 3 + SB];
      acc[dt][0] = MFMA16(a[SA][kc][0], bf, acc[dt][0]);
      acc[dt][1] = MFMA16(a[SA][kc][1], bf, acc[dt][1]);
    }
}

// epilogue for d-tile DT: Y re-layout via identity-B MFMA, masked softmax
// over k (shfl_xor across the 4 lane-groups), returns T[d] = sum_k y_k[d]*gate
template <int DT>
__device__ __forceinline__ float d1_epi(const bf16x8 (&a)[3][2][2],
                                        bf16x8 id0, bf16x8 id1,
                                        const f32x4 (&acc)[4][2], int g) {
  constexpr int KC = DT >> 1;
  const bf16x8 idp = (DT & 1) ? id1 : id0;
  f32x4 yf0 = {0.f, 0.f, 0.f, 0.f}, yf1 = {0.f, 0.f, 0.f, 0.f};
  yf0 = MFMA16(a[1][KC][0], idp, yf0);   // m split first (smaller)
  yf0 = MFMA16(a[0][KC][0], idp, yf0);
  yf1 = MFMA16(a[1][KC][1], idp, yf1);
  yf1 = MFMA16(a[0][KC][1], idp, yf1);
  const f32x4 h0 = acc[DT][0], h1 = acc[DT][1];
  float mx = fmaxf(fmaxf(h0[0], h0[1]), fmaxf(h0[2], h0[3]));
  mx = fmaxf(mx, fmaxf(fmaxf(h1[0], h1[1]), fmaxf(h1[2], h1[3])));  // dups harmless
  mx = fmaxf(mx, __shfl_xor(mx, 16));
  mx = fmaxf(mx, __shfl_xor(mx, 32));
  float sl = 0.f, tl = 0.f;
  #pragma unroll
  for (int j = 0; j < 4; ++j) {
    const float e = __expf(h0[j] - mx);
    sl += e; tl += yf0[j] * e;
  }
  if (g == 0) {   // tile1 rows k=16..19 counted exactly once (dup groups masked)
    #pragma unroll
    for (int j = 0; j < 4; ++j) {
      const float e = __expf(h1[j] - mx);
      sl += e; tl += yf1[j] * e;
    }
  }
  sl += __shfl_xor(sl, 16); sl += __shfl_xor(sl, 32);
  tl += __shfl_xor(tl, 16); tl += __shfl_xor(tl, 32);
  return tl / sl;
}

// ---------------------------------------------------------------------------
// d1 (MFMA rewrite; unchanged from round-3 pass).
// ---------------------------------------------------------------------------
__global__ __launch_bounds__(256, 2) void d1_kernel(
    const unsigned short* __restrict__ xs, const int* __restrict__ fidx,
    const unsigned short* __restrict__ w1p, float* __restrict__ gbuf) {
  const int tid = threadIdx.x;
  const int w = tid >> 6;
  const int lane = tid & 63;
  const int r = lane & 15;
  const int g = lane >> 4;
  const int b = blockIdx.y;
  const char* xsb = ((const char*)xs) + (size_t)b * NN * 384;

  // hoisted n-invariant B-frags (96 VGPR)
  bf16x8 w1f[24];
  #pragma unroll
  for (int f = 0; f < 24; ++f)
    w1f[f] = *(const bf16x8*)(((const char*)w1p) + f * 1024 + lane * 16);

  // identity B-frags: select cols [p*16, p*16+16) of the K=32 chunk
  bf16x8 id0, id1;
  #pragma unroll
  for (int j = 0; j < 8; ++j) {
    id0[j] = (g == (r >> 3) && j == (r & 7)) ? (short)0x3F80 : (short)0;
    id1[j] = (g == 2 + (r >> 3) && j == (r & 7)) ? (short)0x3F80 : (short)0;
  }

  for (int i = 0; i < 4; ++i) {
    const int n = blockIdx.x * 16 + w * 4 + i;
    const size_t ng = (size_t)b * NN + n;
    const int* kp = fidx + ng * KK;
    const int row0 = kp[r];                 // tile0 row r -> neighbor r
    const int row1 = kp[16 + (r & 3)];      // tile1 row r -> neighbor 16+(r&3)
    const char* rp0 = xsb + (size_t)row0 * 384;
    const char* rp1 = xsb + (size_t)row1 * 384;
    const int sw0 = (row0 & 7) << 4, sw1 = (row1 & 7) << 4;

    bf16x8 a[3][2][2];
    #pragma unroll
    for (int s = 0; s < 3; ++s)
      #pragma unroll
      for (int kc = 0; kc < 2; ++kc) {
        const int off = s * 128 + kc * 64 + g * 16;
        a[s][kc][0] = *(const bf16x8*)(rp0 + (off ^ sw0));
        a[s][kc][1] = *(const bf16x8*)(rp1 + (off ^ sw1));
      }

    // z[c=lane] reconstructed to ~2^-27
    const char* zrow = xsb + (size_t)n * 384;
    const int swn = (n & 7) << 4;
    float zl;
    {
      const unsigned short zh = *(const unsigned short*)(zrow + ((2 * lane) ^ swn));
      const unsigned short zm = *(const unsigned short*)(zrow + ((128 + 2 * lane) ^ swn));
      const unsigned short zo = *(const unsigned short*)(zrow + ((256 + 2 * lane) ^ swn));
      zl = bf_f(zh) + bf_f(zm) + bf_f(zo);
    }

    f32x4 acc[4][2];
    #pragma unroll
    for (int dt = 0; dt < 4; ++dt) {
      acc[dt][0] = (f32x4){0.f, 0.f, 0.f, 0.f};
      acc[dt][1] = (f32x4){0.f, 0.f, 0.f, 0.f};
    }
    // smallest cross terms first
    h_term<2, 0>(a, w1f, acc);
    h_term<0, 2>(a, w1f, acc);
    h_term<1, 1>(a, w1f, acc);
    h_term<1, 0>(a, w1f, acc);
    h_term<0, 1>(a, w1f, acc);
    h_term<0, 0>(a, w1f, acc);

    const float t0 = d1_epi<0>(a, id0, id1, acc, g);
    const float t1 = d1_epi<1>(a, id0, id1, acc, g);
    const float t2 = d1_epi<2>(a, id0, id1, acc, g);
    const float t3 = d1_epi<3>(a, id0, id1, acc, g);

    float* go = gbuf + ng * DD;
    go[64 + lane] = zl;                     // g[d>=64] = z  (sum gate == 1)
    const float z0 = __shfl(zl, r);
    const float z1 = __shfl(zl, 16 + r);
    const float z2 = __shfl(zl, 32 + r);
    const float z3 = __shfl(zl, 48 + r);
    if (lane < 16) {
      go[r]      = t0 - z0;
      go[16 + r] = t1 - z1;
      go[32 + r] = t2 - z2;
      go[48 + r] = t3 - z3;
    }
  }
}

// ---------------------------------------------------------------------------
// d2: out[b][o][n] = sum_c g[b][n][c] * W2[o][c]. (unchanged)
// ---------------------------------------------------------------------------
__global__ __launch_bounds__(256) void d2_kernel(const float* __restrict__ gbuf,
                                                 const float* __restrict__ W2,
                                                 float* __restrict__ out) {
  __shared__ float4 w2s[OO * 32];  // addr4 = o*32 + (c4 ^ (o&7))
  const int tid = threadIdx.x;
  const int b = blockIdx.y;
  const int n0 = blockIdx.x * 32;
  const float4* w2v = (const float4*)W2;
  for (int t = tid; t < OO * 32; t += 256) {
    int o = t >> 5, c4 = t & 31;
    w2s[o * 32 + (c4 ^ (o & 7))] = w2v[t];
  }
  __syncthreads();
  const int og = tid & 7;
  const int ni = tid >> 3;
  const int n = n0 + ni;
  const float4* gp = (const float4*)(gbuf + ((size_t)b * NN + n) * DD);
  float acc[16];
  #pragma unroll
  for (int j = 0; j < 16; ++j) acc[j] = 0.0f;
  for (int c4 = 0; c4 < 32; ++c4) {
    float4 g4 = gp[c4];
    #pragma unroll
    for (int j = 0; j < 16; ++j) {
      const int o = j * 8 + og;
      float4 w4 = w2s[o * 32 + (c4 ^ og)];
      acc[j] += g4.x * w4.x + g4.y * w4.y + g4.z * w4.z + g4.w * w4.w;
    }
  }
  float* outb = out + (size_t)b * OO * NN;
  #pragma unroll
  for (int j = 0; j < 16; ++j) {
    outb[(size_t)(j * 8 + og) * NN + n] = acc[j];
  }
}

// ---------------------------------------------------------------------------
// ws layout (bytes):
//   xs    @ 0          : 6,291,456 u16 = 12,582,912 B  (live: prep->knn,d1)
//   xx    @ 12,582,912 :    32,768 f32 =    131,072 B  (live: prep->knn)
//   w1p   @ 12,582,912 :    12,288 u16 =     24,576 B  (aliases dead xx; w1prep->d1)
//   fidx  @ 12,713,984 :   655,360 i32 =  2,621,440 B  (live: merge->d1)
//   pkeys @ 15,335,424 : 1,310,720 u64 = 10,485,760 B  (live: knn->merge; front of gbuf)
//   gbuf  @ 15,335,424 : 4,194,304 f32 = 16,777,216 B  (live: d1->d2; reuses pkeys)
// total: 32,112,640 B
// ---------------------------------------------------------------------------
extern "C" void kernel_launch(void* const* d_in, const int* in_sizes, int n_in,
                              void* d_out, int out_size, void* d_ws, size_t ws_size,
                              hipStream_t stream) {
  const float* x  = (const float*)d_in[0];
  const float* W1 = (const float*)d_in[1];
  const float* W2 = (const float*)d_in[2];
  float* out = (float*)d_out;
  char* ws = (char*)d_ws;
  unsigned short* xs = (unsigned short*)(ws);
  float* xx = (float*)(ws + 12582912);
  unsigned short* w1p = (unsigned short*)(ws + 12582912);
  int* fidx = (int*)(ws + 12713984);
  u64* pkeys = (u64*)(ws + 15335424);
  float* gbuf = (float*)(ws + 15335424);

  prep_kernel<<<dim3(NN / 128, BB), 128, 0, stream>>>(x, xx, xs);
  knn_kernel<<<dim3(1024), 256, 0, stream>>>(xs, xx, pkeys);   // r7 grid, 16 waves/CU
  merge_kernel<<<dim3(BB * NN / 256), 256, 0, stream>>>(pkeys, fidx);
  w1prep_kernel<<<dim3(1), 256, 0, stream>>>(W1, w1p);         // after knn: xx dead
  d1_kernel<<<dim3(NN / 16, BB), 256, 0, stream>>>(xs, fidx, w1p, gbuf);
  d2_kernel<<<dim3(NN / 32, BB), 256, 0, stream>>>(gbuf, W2, out);
}

// Round 14
// 705.272 us; speedup vs baseline: 1.2980x; 1.0026x over previous
//
#include <hip/hip_runtime.h>
#include <math.h>

#define BB 4
#define CC 64
#define NN 8192
#define OO 128
#define KK 20
#define DD 128            // 2*CC
#define NCH 2             // candidate chunks per query
#define CH (NN / NCH)     // 4096 candidates per chunk
#define TC 64             // candidates per tile (r7-proven)
#define NT (CH / TC)      // 64 tiles per sweep
#define BUFSZ 8           // per-lane append slots; checked per subtile (cnt<=4 -> +4 -> <=8)

typedef short bf16x8 __attribute__((ext_vector_type(8)));   // 8 bf16 (4 VGPR)
typedef float f32x4 __attribute__((ext_vector_type(4)));
typedef unsigned short u16x8 __attribute__((ext_vector_type(8)));
typedef unsigned long long u64;

typedef __attribute__((address_space(1))) const void gvoid;
typedef __attribute__((address_space(3))) void lvoid;

#define MFMA16(A, B, C) __builtin_amdgcn_mfma_f32_16x16x32_bf16((A), (B), (C), 0, 0, 0)

// orderable-key packing: (float value, candidate idx) -> u64, so that
// u64-descending == (value desc, idx asc). Matches jax.lax.top_k tie-breaking.
__device__ __forceinline__ u64 packkey(float v, int idx) {
  unsigned u = __float_as_uint(v);
  unsigned o = ((int)u < 0) ? ~u : (u | 0x80000000u);
  return (((u64)o) << 32) | (unsigned)(~idx);
}
__device__ __forceinline__ float keyval(u64 k) {
  unsigned o = (unsigned)(k >> 32);
  unsigned u = (o & 0x80000000u) ? (o ^ 0x80000000u) : ~o;
  return __uint_as_float(u);
}
#define INITKEY (((u64)0x007FFFFFu) << 32)   // packkey(-inf, 0xFFFFFFFF)

__device__ __forceinline__ unsigned short bf_rne(float f) {
  unsigned u = __float_as_uint(f);
  u += 0x7FFFu + ((u >> 16) & 1u);
  return (unsigned short)(u >> 16);
}
__device__ __forceinline__ float bf_f(unsigned short h) {
  return __uint_as_float(((unsigned)h) << 16);
}

// ---------------------------------------------------------------------------
// prep: xx[b][n] and xs[b][n][192] = 3-way bf16 split [h(64)|m(64)|l(64)],
// PRE-SWIZZLED: 16B-group at logical byte o lands at o ^ ((n&7)<<4).
// ---------------------------------------------------------------------------
__global__ __launch_bounds__(128) void prep_kernel(const float* __restrict__ x,
                                                   float* __restrict__ xx,
                                                   unsigned short* __restrict__ xs) {
  const int tid = threadIdx.x;
  const int b = blockIdx.y;
  const int n0 = blockIdx.x * 128;
  const float* xb = x + (size_t)b * CC * NN;
  float xv[CC];
  float acc = 0.0f;
  #pragma unroll
  for (int c = 0; c < CC; ++c) {
    float v = xb[(size_t)c * NN + n0 + tid];   // coalesced over tid
    acc += v * v;
    xv[c] = v;
  }
  xx[b * NN + n0 + tid] = acc;

  const int n = n0 + tid;
  char* xsrow = ((char*)xs) + ((size_t)b * NN + n) * 384;
  const int swn = (n & 7) << 4;
  #pragma unroll
  for (int gr = 0; gr < 8; ++gr) {
    u16x8 h8, m8, l8;
    #pragma unroll
    for (int e = 0; e < 8; ++e) {
      float v = xv[gr * 8 + e];
      unsigned short h = bf_rne(v);
      float r = v - bf_f(h);
      unsigned short m = bf_rne(r);
      r -= bf_f(m);
      unsigned short l = bf_rne(r);
      h8[e] = (unsigned short)h; m8[e] = m; l8[e] = l;
    }
    *(u16x8*)(xsrow + (((gr * 16) + 0) ^ swn)) = h8;
    *(u16x8*)(xsrow + (((gr * 16) + 128) ^ swn)) = m8;
    *(u16x8*)(xsrow + (((gr * 16) + 256) ^ swn)) = l8;
  }
}

// ---------------------------------------------------------------------------
// knn: MFMA distance matrix + per-lane buffered top-20. SESSION-FINAL FORM
// (r13-verified, 707us total): r7 structure (TC=64, NCH=2, 16 waves/CU),
// EXACT 18-MFMA arithmetic (selection bit-identical to every passing round;
// r12 proved the 6-term cut flips selections), transposed [slot][lane]
// append buffers (bank conflicts 3.1M->1.2M), hoisted tile-invariant LDS
// offsets. launch_bounds(256,4) is the only spill-safe bound (r8/r9: higher
// 2nd-arg starves the unified VGPR file -> tk[20] spills to scratch, GBs of
// HBM traffic). Structural assessment after 13 measured rounds: no pipe
// saturated (VALU 53%, MFMA 23%, HBM 0.5%) but every lever (scheduling,
// ILP, cache locality, occupancy x4, instruction count) is A/B-measured;
// the barrier-synchronized selection sweep is at its practical limit.
// ---------------------------------------------------------------------------
__global__ __launch_bounds__(256, 4) void knn_kernel(
    const unsigned short* __restrict__ xs, const float* __restrict__ xx,
    u64* __restrict__ pkeys) {
  __shared__ __attribute__((aligned(16))) unsigned short atile[TC * 192];  // 24576 B
  __shared__ __attribute__((aligned(16))) char bufmem[12288];              // 12288 B
  __shared__ float cxx[TC];                                                //   256 B
  float* pdb = (float*)bufmem;                        // [4][BUFSZ][64] f32 (8192 B)
  unsigned short* idb = (unsigned short*)(bufmem + 8192);  // [4][BUFSZ][64] u16

  const int tid = threadIdx.x;
  const int w = tid >> 6;
  const int lane = tid & 63;
  const int r = lane & 15;    // query col (B) / cand row (A) within subtile
  const int g = lane >> 4;    // k-group
  // XCD-aware map: lin = qg*8 + b*2 + ch; each XCD serves one (batch,
  // chunk): 1.57MB candidate rows, L2-resident.
  const int lin = blockIdx.x;
  const int xcd = lin & 7;
  const int b = xcd >> 1;
  const int ch = xcd & 1;
  const int qg = lin >> 3;           // [0,128)
  const int qbase = qg * 64 + w * 16;
  const int q = qbase + r;
  const int cbase = ch * CH;
  const char* xsb = ((const char*)xs) + (size_t)b * NN * 384;

  // query B-frags: bq[split][k-chunk]; lane holds k = (lane>>4)*8+[0..8) of 32
  bf16x8 bq[3][2];
  {
    const char* qrow = xsb + (size_t)q * 384;
    const int sw = (q & 7) << 4;
    #pragma unroll
    for (int s = 0; s < 3; ++s)
      #pragma unroll
      for (int c = 0; c < 2; ++c)
        bq[s][c] = *(const bf16x8*)(qrow + ((s * 128 + c * 64 + g * 16) ^ sw));
  }
  const float xxq = xx[b * NN + q];

  // tile-invariant LDS read offsets (24 ints)
  int aoff[4][6];
  {
    const int sw = (r & 7) << 4;
    #pragma unroll
    for (int ct = 0; ct < 4; ++ct)
      #pragma unroll
      for (int c6 = 0; c6 < 6; ++c6)
        aoff[ct][c6] = (ct * 16 + r) * 384 + ((c6 * 64 + g * 16) ^ sw);
  }

  u64 tk[KK];
  #pragma unroll
  for (int j = 0; j < KK; ++j) tk[j] = INITKEY;
  float minv = -INFINITY;
  int cnt = 0;
  float* pdl = pdb + w * (BUFSZ * 64) + lane;          // [slot][lane]: stride 64
  unsigned short* idl = idb + w * (BUFSZ * 64) + lane;

  // stage tile t (24576 B: six 256-thread x 16B rounds)
  auto stage = [&](int t) {
    const char* src = xsb + (size_t)(cbase + t * TC) * 384;
    char* dst = (char*)atile;
    #pragma unroll
    for (int it = 0; it < 6; ++it) {
      __builtin_amdgcn_global_load_lds(
          (gvoid*)(src + it * 4096 + tid * 16),
          (lvoid*)(dst + it * 4096 + tid * 16), 16, 0, 0);
    }
    if (tid < 16)
      __builtin_amdgcn_global_load_lds(
          (gvoid*)(xx + b * NN + cbase + t * TC + tid * 4),
          (lvoid*)(cxx + tid * 4), 16, 0, 0);
  };

  // fold buffered candidates into the register-sorted top-20, tighten minv
  auto rebuild = [&]() {
    int mxc = cnt;
    #pragma unroll
    for (int o = 32; o > 0; o >>= 1) {
      int v = __shfl_xor(mxc, o);
      mxc = mxc > v ? mxc : v;
    }
    for (int i = 0; i < mxc; ++i) {
      u64 k = (i < cnt) ? packkey(pdl[i * 64], (int)idl[i * 64]) : 0ULL;
      if (k > tk[KK - 1]) {
        #pragma unroll
        for (int jj = KK - 1; jj >= 1; --jj)
          tk[jj] = (k > tk[jj - 1]) ? tk[jj - 1] : ((k > tk[jj]) ? k : tk[jj]);
        tk[0] = (k > tk[0]) ? k : tk[0];
      }
    }
    cnt = 0;
    minv = keyval(tk[KK - 1]);
  };

  for (int t = 0; t < NT; ++t) {
    stage(t);
    __syncthreads();   // vmcnt drained by compiler before barrier

    #pragma unroll
    for (int ct = 0; ct < 4; ++ct) {
      bf16x8 a6[6];
      #pragma unroll
      for (int c6 = 0; c6 < 6; ++c6)
        a6[c6] = *(const bf16x8*)(((const char*)atile) + aoff[ct][c6]);
      f32x4 acc = {0.f, 0.f, 0.f, 0.f};
      __builtin_amdgcn_s_setprio(1);
      // FULL 9-term cross product, EXACT r7 order (s=2..0, c6=0..5):
      // selection bit-identical to every passing round.
      #pragma unroll
      for (int s = 2; s >= 0; --s)
        #pragma unroll
        for (int c6 = 0; c6 < 6; ++c6)
          acc = MFMA16(a6[c6], bq[s][c6 & 1], acc);
      __builtin_amdgcn_s_setprio(0);

      // branchless pds + append gate (skips whole block once minv is tight)
      float pd0 = (-xxq - (-2.0f * acc[0])) - cxx[ct * 16 + g * 4 + 0];
      float pd1 = (-xxq - (-2.0f * acc[1])) - cxx[ct * 16 + g * 4 + 1];
      float pd2 = (-xxq - (-2.0f * acc[2])) - cxx[ct * 16 + g * 4 + 2];
      float pd3 = (-xxq - (-2.0f * acc[3])) - cxx[ct * 16 + g * 4 + 3];
      const float maxpd = fmaxf(fmaxf(pd0, pd1), fmaxf(pd2, pd3));
      if (__any(maxpd > minv)) {
        const int i0 = cbase + t * TC + ct * 16 + g * 4;
        if (pd0 > minv) { pdl[cnt * 64] = pd0; idl[cnt * 64] = (unsigned short)(i0 + 0); ++cnt; }
        if (pd1 > minv) { pdl[cnt * 64] = pd1; idl[cnt * 64] = (unsigned short)(i0 + 1); ++cnt; }
        if (pd2 > minv) { pdl[cnt * 64] = pd2; idl[cnt * 64] = (unsigned short)(i0 + 2); ++cnt; }
        if (pd3 > minv) { pdl[cnt * 64] = pd3; idl[cnt * 64] = (unsigned short)(i0 + 3); ++cnt; }
        // invariant: cnt<=4 entering a subtile; +4 appends -> <=8 = BUFSZ
        if (__any(cnt > BUFSZ - 4)) rebuild();
      }
    }
    __syncthreads();   // atile consumed; next stage may overwrite
  }

  rebuild();   // flush remaining buffered candidates

  // --- epilogue: 4-class in-block merge -> pkeys[q][ch][20] ---
  // atile (24,576 B) + bufmem (12,288 B) dead; 2 waves per pass, 10,240 B each.
  for (int pass = 0; pass < 2; ++pass) {
    __syncthreads();
    if ((w >> 1) == pass) {
      u64* ml = (w & 1) ? (u64*)bufmem : (u64*)atile;
      #pragma unroll
      for (int j = 0; j < KK; ++j) ml[lane * KK + j] = tk[j];
      // same-wave LDS write->read: in-order, compiler inserts lgkmcnt
      if (lane < 16) {
        u64* po = pkeys + (((size_t)b * NN + qbase + lane) * NCH + ch) * KK;
        const u64* L0 = ml + (lane + 0) * KK;
        const u64* L1 = ml + (lane + 16) * KK;
        const u64* L2 = ml + (lane + 32) * KK;
        const u64* L3 = ml + (lane + 48) * KK;
        int p0 = 0, p1 = 0, p2 = 0, p3 = 0;
        u64 h0 = L0[0], h1 = L1[0], h2 = L2[0], h3 = L3[0];
        #pragma unroll
        for (int k = 0; k < KK; ++k) {
          u64 bv = h0; int bc = 0;
          if (h1 > bv) { bv = h1; bc = 1; }
          if (h2 > bv) { bv = h2; bc = 2; }
          if (h3 > bv) { bv = h3; bc = 3; }
          po[k] = bv;
          if (bc == 0)      { ++p0; h0 = (p0 < KK) ? L0[p0] : 0ULL; }
          else if (bc == 1) { ++p1; h1 = (p1 < KK) ? L1[p1] : 0ULL; }
          else if (bc == 2) { ++p2; h2 = (p2 < KK) ? L2[p2] : 0ULL; }
          else              { ++p3; h3 = (p3 < KK) ? L3[p3] : 0ULL; }
        }
      }
    }
  }
}

// ---------------------------------------------------------------------------
// merge: per query, 2-way merge of the two chunk lists (sorted desc u64).
// Chunks partition index ranges; u64 compare embeds (value desc, idx asc).
// ---------------------------------------------------------------------------
__global__ __launch_bounds__(256) void merge_kernel(const u64* __restrict__ pkeys,
                                                    int* __restrict__ fidx) {
  const int q = blockIdx.x * 256 + threadIdx.x;   // q = b*NN + n
  const u64* pk = pkeys + (size_t)q * NCH * KK;
  int* fo = fidx + (size_t)q * KK;
  int p0 = 0, p1 = 0;
  u64 h0 = pk[0], h1 = pk[KK];
  #pragma unroll
  for (int k = 0; k < KK; ++k) {
    const bool t1 = h1 > h0;
    const u64 bv = t1 ? h1 : h0;
    fo[k] = (int)(~(unsigned)bv);
    if (t1) { ++p1; h1 = (p1 < KK) ? pk[KK + p1] : 0ULL; }
    else    { ++p0; h0 = (p0 < KK) ? pk[p0] : 0ULL; }
  }
}

// ---------------------------------------------------------------------------
// w1prep: pre-pack W1a^T as 3-way bf16-split MFMA B-frags.
// ---------------------------------------------------------------------------
__global__ __launch_bounds__(256) void w1prep_kernel(const float* __restrict__ W1,
                                                     unsigned short* __restrict__ w1p) {
  for (int e = threadIdx.x; e < 12288; e += 256) {
    const int f = e >> 9;
    const int rr = e & 511;
    const int l = rr >> 3;
    const int j = rr & 7;
    const int pair = f / 3, s = f % 3;
    const int dt = pair >> 1, kc = pair & 1;
    const int d = dt * 16 + (l & 15);
    const int c = kc * 32 + (l >> 4) * 8 + j;
    const float v = W1[d * DD + c];
    const unsigned short h = bf_rne(v);
    float r = v - bf_f(h);
    const unsigned short m = bf_rne(r);
    r -= bf_f(m);
    const unsigned short lo = bf_rne(r);
    w1p[(size_t)f * 512 + l * 8 + j] = (s == 0) ? h : ((s == 1) ? m : lo);
  }
}

// one h-GEMM cross term (SA = A split, SB = B split), indices compile-time
template <int SA, int SB>
__device__ __forceinline__ void h_term(const bf16x8 (&a)[3][2][2],
                                       const bf16x8 (&w1f)[24],
                                       f32x4 (&acc)[4][2]) {
  #pragma unroll
  for (int dt = 0; dt < 4; ++dt)
    #pragma unroll
    for (int kc = 0; kc < 2; ++kc) {
      const bf16x8 bf = w1f[(dt * 2 + kc) * 3 + SB];
      acc[dt][0] = MFMA16(a[SA][kc][0], bf, acc[dt][0]);
      acc[dt][1] = MFMA16(a[SA][kc][1], bf, acc[dt][1]);
    }
}

// epilogue for d-tile DT: Y re-layout via identity-B MFMA, masked softmax
// over k (shfl_xor across the 4 lane-groups), returns T[d] = sum_k y_k[d]*gate
template <int DT>
__device__ __forceinline__ float d1_epi(const bf16x8 (&a)[3][2][2],
                                        bf16x8 id0, bf16x8 id1,
                                        const f32x4 (&acc)[4][2], int g) {
  constexpr int KC = DT >> 1;
  const bf16x8 idp = (DT & 1) ? id1 : id0;
  f32x4 yf0 = {0.f, 0.f, 0.f, 0.f}, yf1 = {0.f, 0.f, 0.f, 0.f};
  yf0 = MFMA16(a[1][KC][0], idp, yf0);   // m split first (smaller)
  yf0 = MFMA16(a[0][KC][0], idp, yf0);
  yf1 = MFMA16(a[1][KC][1], idp, yf1);
  yf1 = MFMA16(a[0][KC][1], idp, yf1);
  const f32x4 h0 = acc[DT][0], h1 = acc[DT][1];
  float mx = fmaxf(fmaxf(h0[0], h0[1]), fmaxf(h0[2], h0[3]));
  mx = fmaxf(mx, fmaxf(fmaxf(h1[0], h1[1]), fmaxf(h1[2], h1[3])));  // dups harmless
  mx = fmaxf(mx, __shfl_xor(mx, 16));
  mx = fmaxf(mx, __shfl_xor(mx, 32));
  float sl = 0.f, tl = 0.f;
  #pragma unroll
  for (int j = 0; j < 4; ++j) {
    const float e = __expf(h0[j] - mx);
    sl += e; tl += yf0[j] * e;
  }
  if (g == 0) {   // tile1 rows k=16..19 counted exactly once (dup groups masked)
    #pragma unroll
    for (int j = 0; j < 4; ++j) {
      const float e = __expf(h1[j] - mx);
      sl += e; tl += yf1[j] * e;
    }
  }
  sl += __shfl_xor(sl, 16); sl += __shfl_xor(sl, 32);
  tl += __shfl_xor(tl, 16); tl += __shfl_xor(tl, 32);
  return tl / sl;
}

// ---------------------------------------------------------------------------
// d1 (MFMA rewrite; unchanged from round-3 pass).
// ---------------------------------------------------------------------------
__global__ __launch_bounds__(256, 2) void d1_kernel(
    const unsigned short* __restrict__ xs, const int* __restrict__ fidx,
    const unsigned short* __restrict__ w1p, float* __restrict__ gbuf) {
  const int tid = threadIdx.x;
  const int w = tid >> 6;
  const int lane = tid & 63;
  const int r = lane & 15;
  const int g = lane >> 4;
  const int b = blockIdx.y;
  const char* xsb = ((const char*)xs) + (size_t)b * NN * 384;

  // hoisted n-invariant B-frags (96 VGPR)
  bf16x8 w1f[24];
  #pragma unroll
  for (int f = 0; f < 24; ++f)
    w1f[f] = *(const bf16x8*)(((const char*)w1p) + f * 1024 + lane * 16);

  // identity B-frags: select cols [p*16, p*16+16) of the K=32 chunk
  bf16x8 id0, id1;
  #pragma unroll
  for (int j = 0; j < 8; ++j) {
    id0[j] = (g == (r >> 3) && j == (r & 7)) ? (short)0x3F80 : (short)0;
    id1[j] = (g == 2 + (r >> 3) && j == (r & 7)) ? (short)0x3F80 : (short)0;
  }

  for (int i = 0; i < 4; ++i) {
    const int n = blockIdx.x * 16 + w * 4 + i;
    const size_t ng = (size_t)b * NN + n;
    const int* kp = fidx + ng * KK;
    const int row0 = kp[r];                 // tile0 row r -> neighbor r
    const int row1 = kp[16 + (r & 3)];      // tile1 row r -> neighbor 16+(r&3)
    const char* rp0 = xsb + (size_t)row0 * 384;
    const char* rp1 = xsb + (size_t)row1 * 384;
    const int sw0 = (row0 & 7) << 4, sw1 = (row1 & 7) << 4;

    bf16x8 a[3][2][2];
    #pragma unroll
    for (int s = 0; s < 3; ++s)
      #pragma unroll
      for (int kc = 0; kc < 2; ++kc) {
        const int off = s * 128 + kc * 64 + g * 16;
        a[s][kc][0] = *(const bf16x8*)(rp0 + (off ^ sw0));
        a[s][kc][1] = *(const bf16x8*)(rp1 + (off ^ sw1));
      }

    // z[c=lane] reconstructed to ~2^-27
    const char* zrow = xsb + (size_t)n * 384;
    const int swn = (n & 7) << 4;
    float zl;
    {
      const unsigned short zh = *(const unsigned short*)(zrow + ((2 * lane) ^ swn));
      const unsigned short zm = *(const unsigned short*)(zrow + ((128 + 2 * lane) ^ swn));
      const unsigned short zo = *(const unsigned short*)(zrow + ((256 + 2 * lane) ^ swn));
      zl = bf_f(zh) + bf_f(zm) + bf_f(zo);
    }

    f32x4 acc[4][2];
    #pragma unroll
    for (int dt = 0; dt < 4; ++dt) {
      acc[dt][0] = (f32x4){0.f, 0.f, 0.f, 0.f};
      acc[dt][1] = (f32x4){0.f, 0.f, 0.f, 0.f};
    }
    // smallest cross terms first
    h_term<2, 0>(a, w1f, acc);
    h_term<0, 2>(a, w1f, acc);
    h_term<1, 1>(a, w1f, acc);
    h_term<1, 0>(a, w1f, acc);
    h_term<0, 1>(a, w1f, acc);
    h_term<0, 0>(a, w1f, acc);

    const float t0 = d1_epi<0>(a, id0, id1, acc, g);
    const float t1 = d1_epi<1>(a, id0, id1, acc, g);
    const float t2 = d1_epi<2>(a, id0, id1, acc, g);
    const float t3 = d1_epi<3>(a, id0, id1, acc, g);

    float* go = gbuf + ng * DD;
    go[64 + lane] = zl;                     // g[d>=64] = z  (sum gate == 1)
    const float z0 = __shfl(zl, r);
    const float z1 = __shfl(zl, 16 + r);
    const float z2 = __shfl(zl, 32 + r);
    const float z3 = __shfl(zl, 48 + r);
    if (lane < 16) {
      go[r]      = t0 - z0;
      go[16 + r] = t1 - z1;
      go[32 + r] = t2 - z2;
      go[48 + r] = t3 - z3;
    }
  }
}

// ---------------------------------------------------------------------------
// d2: out[b][o][n] = sum_c g[b][n][c] * W2[o][c].
// ---------------------------------------------------------------------------
__global__ __launch_bounds__(256) void d2_kernel(const float* __restrict__ gbuf,
                                                 const float* __restrict__ W2,
                                                 float* __restrict__ out) {
  __shared__ float4 w2s[OO * 32];  // addr4 = o*32 + (c4 ^ (o&7))
  const int tid = threadIdx.x;
  const int b = blockIdx.y;
  const int n0 = blockIdx.x * 32;
  const float4* w2v = (const float4*)W2;
  for (int t = tid; t < OO * 32; t += 256) {
    int o = t >> 5, c4 = t & 31;
    w2s[o * 32 + (c4 ^ (o & 7))] = w2v[t];
  }
  __syncthreads();
  const int og = tid & 7;
  const int ni = tid >> 3;
  const int n = n0 + ni;
  const float4* gp = (const float4*)(gbuf + ((size_t)b * NN + n) * DD);
  float acc[16];
  #pragma unroll
  for (int j = 0; j < 16; ++j) acc[j] = 0.0f;
  for (int c4 = 0; c4 < 32; ++c4) {
    float4 g4 = gp[c4];
    #pragma unroll
    for (int j = 0; j < 16; ++j) {
      const int o = j * 8 + og;
      float4 w4 = w2s[o * 32 + (c4 ^ og)];
      acc[j] += g4.x * w4.x + g4.y * w4.y + g4.z * w4.z + g4.w * w4.w;
    }
  }
  float* outb = out + (size_t)b * OO * NN;
  #pragma unroll
  for (int j = 0; j < 16; ++j) {
    outb[(size_t)(j * 8 + og) * NN + n] = acc[j];
  }
}

// ---------------------------------------------------------------------------
// ws layout (bytes):
//   xs    @ 0          : 6,291,456 u16 = 12,582,912 B  (live: prep->knn,d1)
//   xx    @ 12,582,912 :    32,768 f32 =    131,072 B  (live: prep->knn)
//   w1p   @ 12,582,912 :    12,288 u16 =     24,576 B  (aliases dead xx; w1prep->d1)
//   fidx  @ 12,713,984 :   655,360 i32 =  2,621,440 B  (live: merge->d1)
//   pkeys @ 15,335,424 : 1,310,720 u64 = 10,485,760 B  (live: knn->merge; front of gbuf)
//   gbuf  @ 15,335,424 : 4,194,304 f32 = 16,777,216 B  (live: d1->d2; reuses pkeys)
// total: 32,112,640 B
// ---------------------------------------------------------------------------
extern "C" void kernel_launch(void* const* d_in, const int* in_sizes, int n_in,
                              void* d_out, int out_size, void* d_ws, size_t ws_size,
                              hipStream_t stream) {
  const float* x  = (const float*)d_in[0];
  const float* W1 = (const float*)d_in[1];
  const float* W2 = (const float*)d_in[2];
  float* out = (float*)d_out;
  char* ws = (char*)d_ws;
  unsigned short* xs = (unsigned short*)(ws);
  float* xx = (float*)(ws + 12582912);
  unsigned short* w1p = (unsigned short*)(ws + 12582912);
  int* fidx = (int*)(ws + 12713984);
  u64* pkeys = (u64*)(ws + 15335424);
  float* gbuf = (float*)(ws + 15335424);

  prep_kernel<<<dim3(NN / 128, BB), 128, 0, stream>>>(x, xx, xs);
  knn_kernel<<<dim3(1024), 256, 0, stream>>>(xs, xx, pkeys);   // 16 waves/CU
  merge_kernel<<<dim3(BB * NN / 256), 256, 0, stream>>>(pkeys, fidx);
  w1prep_kernel<<<dim3(1), 256, 0, stream>>>(W1, w1p);         // after knn: xx dead
  d1_kernel<<<dim3(NN / 16, BB), 256, 0, stream>>>(xs, fidx, w1p, gbuf);
  d2_kernel<<<dim3(NN / 32, BB), 256, 0, stream>>>(gbuf, W2, out);
}